// Round 6
// baseline (308.029 us; speedup 1.0000x reference)
//
#include <hip/hip_runtime.h>
#include <float.h>
#include <math.h>

#define DIM    128
#define KCB    8192
#define BT     128               // tokens per block
#define NC     128               // codes per chunk
#define NCHUNK (KCB / NC)

typedef __attribute__((ext_vector_type(8))) short bf16x8;
typedef __attribute__((ext_vector_type(4))) float f32x4;

// persistent scratch as device globals (rewritten every call by vq_prep)
__device__ unsigned g_ehi[KCB * DIM / 2];   // 2 MB packed bf16 pairs, XOR-swizzle pre-baked
__device__ unsigned g_elo[KCB * DIM / 2];   // 2 MB
__device__ float    g_h[KCB];
__device__ unsigned g_counts[KCB];
__device__ double   g_loss;
__device__ unsigned g_done;

__device__ __forceinline__ unsigned short f2b(float x) {      // RNE fp32->bf16
    union { float f; unsigned u; } v; v.f = x;
    unsigned r = v.u + 0x7fffu + ((v.u >> 16) & 1u);
    return (unsigned short)(r >> 16);
}
__device__ __forceinline__ float b2f(unsigned short h) {
    union { unsigned u; float f; } v; v.u = ((unsigned)h) << 16; return v.f;
}
__device__ __forceinline__ void gll16(const void* g, void* l) {   // async global->LDS, 16B/lane
    __builtin_amdgcn_global_load_lds(
        (const __attribute__((address_space(1))) void*)g,
        (__attribute__((address_space(3))) void*)l, 16, 0, 0);
}

// ---------------- prep: split emb into bf16 hi/lo (swizzled), h_k, zero state ----------------
__global__ __launch_bounds__(256) void vq_prep(const float* __restrict__ emb)
{
    const int tid  = threadIdx.x;
    const int gid  = blockIdx.x * 256 + tid;
    if (gid < KCB) g_counts[gid] = 0u;
    if (gid == 0)  { g_loss = 0.0; g_done = 0u; }

    const int code = (blockIdx.x << 2) + (tid >> 6);   // one wave per code
    const int lane = tid & 63;
    const float2 v = ((const float2*)emb)[code * 64 + lane];   // d = 2*lane, 2*lane+1

    unsigned short h0 = f2b(v.x), h1 = f2b(v.y);
    unsigned short l0 = f2b(v.x - b2f(h0)), l1 = f2b(v.y - b2f(h1));
    // stored word widx holds pair (widx ^ swz): read-side XOR on byte bits [6:4]
    const int widx = code * 64 + (lane ^ ((code & 7) << 2));
    g_ehi[widx] = (unsigned)h0 | ((unsigned)h1 << 16);
    g_elo[widx] = (unsigned)l0 | ((unsigned)l1 << 16);

    float s = v.x * v.x + v.y * v.y;
    #pragma unroll
    for (int o = 32; o > 0; o >>= 1) s += __shfl_down(s, o);
    if (lane == 0) g_h[code] = 0.5f * s;
}

// ---------------- main: 3-pass bf16 MFMA distance GEMM + argmin + epilogue + final ----------
// amdgpu_waves_per_eu(2,2): pin allocator to exactly 2 waves/EU -> VGPR cap 256, and no
// gratuitous spilling toward a 128-reg/4-wave target (round-4 regression: 128 VGPR + 30MB scratch)
__global__ __launch_bounds__(512) __attribute__((amdgpu_waves_per_eu(2, 2))) void vq_main(
    const float* __restrict__ z, const float* __restrict__ emb, float* __restrict__ out)
{
    __shared__ char   smem[2 * 65536];        // 2 bufs x (ehi 32KB | elo 32KB), swizzled rows
    __shared__ float  rv[BT * 4];
    __shared__ int    ri[BT * 4];
    __shared__ int    idx_sh[BT];
    __shared__ double wred[8];
    __shared__ int    done_sh;

    const int tid  = threadIdx.x;
    const int lane = tid & 63;
    const int wid  = tid >> 6;                // 8 waves
    const int tg   = wid >> 2;                // token half (64 tokens, M=64/wave)
    const int cq   = wid & 3;                 // code quarter (32 codes/chunk)
    const int l15  = lane & 15;
    const int lg   = lane >> 4;
    const long t0  = (long)blockIdx.x * BT;

    // ---- A fragments: 64 z-rows in registers for the whole kernel (hi + lo bf16 split) ----
    bf16x8 ah[4][4], al[4][4];
    #pragma unroll
    for (int m = 0; m < 4; ++m) {
        const long trow = t0 + tg * 64 + m * 16 + l15;
        #pragma unroll
        for (int kk = 0; kk < 4; ++kk) {
            const float4* zp = (const float4*)(z + trow * DIM + kk * 32 + lg * 8);
            float4 v0 = zp[0], v1 = zp[1];
            float xs[8] = {v0.x, v0.y, v0.z, v0.w, v1.x, v1.y, v1.z, v1.w};
            #pragma unroll
            for (int j = 0; j < 8; ++j) {
                unsigned short hb = f2b(xs[j]);
                ah[m][kk][j] = (short)hb;
                al[m][kk][j] = (short)f2b(xs[j] - b2f(hb));
            }
        }
    }

    // per-lane swizzled LDS byte offsets: row=l15, byte = row*256 + (col ^ ((row&7)<<4))
    const int xr = (l15 & 7) << 4;
    int loff[4];
    #pragma unroll
    for (int kk = 0; kk < 4; ++kk) loff[kk] = l15 * 256 + ((kk * 64 + lg * 16) ^ xr);

    float bv[4][4]; int bi[4][4];
    #pragma unroll
    for (int m = 0; m < 4; ++m)
        #pragma unroll
        for (int r = 0; r < 4; ++r) { bv[m][r] = FLT_MAX; bi[m][r] = 0; }

    // ---- prologue: stage chunk 0 ----
    {
        const int o = tid * 16;               // 512 thr x 16B = 8KB per round
        #pragma unroll
        for (int r = 0; r < 4; ++r)
            gll16((const char*)g_ehi + r * 8192 + o, smem + r * 8192 + o);
        #pragma unroll
        for (int r = 0; r < 4; ++r)
            gll16((const char*)g_elo + r * 8192 + o, smem + 32768 + r * 8192 + o);
    }
    __syncthreads();

    for (int ch = 0; ch < NCHUNK; ++ch) {
        const int cb  = ch * NC;
        const int cur = ch & 1;
        if (ch + 1 < NCHUNK) {                // stage next chunk into the other buffer
            const int  o  = tid * 16;
            const long go = (long)(ch + 1) * 32768;
            char* ldst = smem + (cur ^ 1) * 65536;
            #pragma unroll
            for (int r = 0; r < 4; ++r)
                gll16((const char*)g_ehi + go + r * 8192 + o, ldst + r * 8192 + o);
            #pragma unroll
            for (int r = 0; r < 4; ++r)
                gll16((const char*)g_elo + go + r * 8192 + o, ldst + 32768 + r * 8192 + o);
        }

        const char* base = smem + cur * 65536 + cq * 8192;   // this wave's 32-code quarter
        const int   c0   = cb + cq * 32 + l15;
        float hc[2] = { g_h[c0], g_h[c0 + 16] };             // issue early, hide under MFMA

        #pragma unroll
        for (int n = 0; n < 2; ++n) {
            bf16x8 bh[4], bl[4];
            #pragma unroll
            for (int kk = 0; kk < 4; ++kk) {
                bh[kk] = *(const bf16x8*)(base + n * 4096 + loff[kk]);
                bl[kk] = *(const bf16x8*)(base + 32768 + n * 4096 + loff[kk]);
            }
            f32x4 acc[4];
            #pragma unroll
            for (int m = 0; m < 4; ++m) acc[m] = (f32x4){0.f, 0.f, 0.f, 0.f};
            #pragma unroll
            for (int kk = 0; kk < 4; ++kk) {
                #pragma unroll
                for (int m = 0; m < 4; ++m)
                    acc[m] = __builtin_amdgcn_mfma_f32_16x16x32_bf16(ah[m][kk], bh[kk], acc[m], 0, 0, 0);
                #pragma unroll
                for (int m = 0; m < 4; ++m)
                    acc[m] = __builtin_amdgcn_mfma_f32_16x16x32_bf16(al[m][kk], bh[kk], acc[m], 0, 0, 0);
                #pragma unroll
                for (int m = 0; m < 4; ++m)
                    acc[m] = __builtin_amdgcn_mfma_f32_16x16x32_bf16(ah[m][kk], bl[kk], acc[m], 0, 0, 0);
            }
            // fused running argmin: score = h_c - z.e ; C layout row=lg*4+r, col=l15
            const int c = c0 + n * 16;
            #pragma unroll
            for (int m = 0; m < 4; ++m)
                #pragma unroll
                for (int r = 0; r < 4; ++r) {
                    float sc = hc[n] - acc[m][r];
                    if (sc < bv[m][r]) { bv[m][r] = sc; bi[m][r] = c; }  // ascending: strict <
                }
        }
        __syncthreads();   // all waves done reading cur; drains staged vmcnt
    }

    // ---- argmin reduce across the 16-lane column group ----
    #pragma unroll
    for (int m = 0; m < 4; ++m)
        #pragma unroll
        for (int r = 0; r < 4; ++r) {
            float v = bv[m][r]; int ix = bi[m][r];
            #pragma unroll
            for (int o = 1; o < 16; o <<= 1) {
                float ov = __shfl_xor(v, o);
                int   oi = __shfl_xor(ix, o);
                if (ov < v || (ov == v && oi < ix)) { v = ov; ix = oi; }
            }
            if (l15 == 0) {
                int t = tg * 64 + m * 16 + lg * 4 + r;
                rv[t * 4 + cq] = v; ri[t * 4 + cq] = ix;
            }
        }
    __syncthreads();
    if (tid < BT) {
        float best = rv[tid * 4]; int bidx = ri[tid * 4];
        #pragma unroll
        for (int x = 1; x < 4; ++x) {
            float v = rv[tid * 4 + x]; int i = ri[tid * 4 + x];
            if (v < best || (v == best && i < bidx)) { best = v; bidx = i; }
        }
        idx_sh[tid] = bidx;
        atomicAdd(&g_counts[bidx], 1u);
    }
    __syncthreads();

    // ---- epilogue: gather e[idx], out = z + (zq - z), loss partial ----
    float lsum = 0.f;
    {
        const float4* zf4 = (const float4*)(z + t0 * DIM);
        const float4* ef4 = (const float4*)emb;
        float4*       of4 = (float4*)(out + t0 * DIM);
        #pragma unroll
        for (int r = 0; r < 8; ++r) {
            int f = r * 512 + tid;
            int t = f >> 5, dw = f & 31;
            int ci = idx_sh[t];
            float4 e4 = ef4[(size_t)ci * 32 + dw];
            float4 z4 = zf4[f];
            float dx = e4.x - z4.x, dy = e4.y - z4.y;
            float dz = e4.z - z4.z, dw2 = e4.w - z4.w;
            lsum += dx * dx + dy * dy + dz * dz + dw2 * dw2;
            float4 o;
            o.x = z4.x + dx; o.y = z4.y + dy; o.z = z4.z + dz; o.w = z4.w + dw2;
            of4[f] = o;
        }
    }
    #pragma unroll
    for (int o = 32; o > 0; o >>= 1) lsum += __shfl_down(lsum, o);
    if (lane == 0) wred[wid] = (double)lsum;
    __syncthreads();
    if (tid == 0) {
        double s = 0.0;
        #pragma unroll
        for (int w = 0; w < 8; ++w) s += wred[w];
        atomicAdd(&g_loss, s);
    }

    // ---- last block finishes: perplexity + commit loss (folds vq_final) ----
    __threadfence();
    if (tid == 0) done_sh = (atomicAdd(&g_done, 1u) == gridDim.x - 1) ? 1 : 0;
    __syncthreads();
    if (done_sh) {
        const int ntok    = (int)gridDim.x * BT;
        const int n_elems = ntok * DIM;
        double s = 0.0;
        for (int i = tid; i < KCB; i += 512) {
            unsigned cnt = atomicAdd(&g_counts[i], 0u);      // coherent read
            float em = (float)cnt / (float)ntok;
            s += (double)(em * logf(em + 1e-8f));
        }
        #pragma unroll
        for (int o = 32; o > 0; o >>= 1) s += __shfl_down(s, o);
        if (lane == 0) wred[wid] = s;
        __syncthreads();
        if (tid == 0) {
            double tot = 0.0;
            #pragma unroll
            for (int w = 0; w < 8; ++w) tot += wred[w];
            double L = atomicAdd(&g_loss, 0.0);              // coherent read
            out[(size_t)n_elems]     = (float)(1.25 * L / (double)n_elems);
            out[(size_t)n_elems + 1] = expf((float)(-tot));
        }
    }
}

extern "C" void kernel_launch(void* const* d_in, const int* in_sizes, int n_in,
                              void* d_out, int out_size, void* d_ws, size_t ws_size,
                              hipStream_t stream)
{
    const float* z   = (const float*)d_in[0];
    const float* emb = (const float*)d_in[1];
    float* out = (float*)d_out;

    const int n_elems = in_sizes[0];        // 4194304
    const int ntok    = n_elems / DIM;      // 32768

    vq_prep<<<dim3(KCB / 4),   256, 0, stream>>>(emb);
    vq_main<<<dim3(ntok / BT), 512, 0, stream>>>(z, emb, out);
}

// Round 7
// 303.687 us; speedup vs baseline: 1.0143x; 1.0143x over previous
//
#include <hip/hip_runtime.h>
#include <float.h>
#include <math.h>

#define DIM    128
#define KCB    8192
#define BT     128               // tokens per block
#define NC     128               // codes per chunk
#define NCHUNK (KCB / NC)
#define CAP    32                // refine-candidate cap per token
#define MARGIN 0.016f            // >= 2*(stage1 err bound 5.3e-3) + key-snap slack

typedef __attribute__((ext_vector_type(8))) short bf16x8;
typedef __attribute__((ext_vector_type(4))) float f32x4;

__device__ unsigned g_eh[KCB * DIM / 2];    // 2 MB packed bf16 hi pairs, XOR-swizzle pre-baked
__device__ float    g_h[KCB];
__device__ unsigned g_counts[KCB];
__device__ double   g_loss;
__device__ unsigned g_done;

__device__ __forceinline__ unsigned short f2b(float x) {      // RNE fp32->bf16
    union { float f; unsigned u; } v; v.f = x;
    unsigned r = v.u + 0x7fffu + ((v.u >> 16) & 1u);
    return (unsigned short)(r >> 16);
}
__device__ __forceinline__ void gll16(const void* g, void* l) {   // async global->LDS, 16B/lane
    __builtin_amdgcn_global_load_lds(
        (const __attribute__((address_space(1))) void*)g,
        (__attribute__((address_space(3))) void*)l, 16, 0, 0);
}
// order-preserving fp32->u32 flip, idx stuffed in low 13 bits (ties -> lowest idx wins at min)
__device__ __forceinline__ unsigned pkey(float sc, int c) {
    unsigned u = __float_as_uint(sc);
    u ^= (unsigned)(((int)u >> 31)) | 0x80000000u;
    return (u & ~8191u) | (unsigned)c;
}
__device__ __forceinline__ float key2sc(unsigned k) {
    unsigned u = (k & 0x80000000u) ? (k ^ 0x80000000u) : ~k;
    return __uint_as_float(u);
}

// ---------------- prep: bf16-hi split of emb (swizzled), h_k, zero state ----------------
__global__ __launch_bounds__(256) void vq_prep(const float* __restrict__ emb)
{
    const int tid = threadIdx.x;
    const int gid = blockIdx.x * 256 + tid;
    if (gid < KCB) g_counts[gid] = 0u;
    if (gid == 0)  { g_loss = 0.0; g_done = 0u; }

    const int code = (blockIdx.x << 2) + (tid >> 6);   // one wave per code
    const int lane = tid & 63;
    const float2 v = ((const float2*)emb)[code * 64 + lane];

    unsigned short h0 = f2b(v.x), h1 = f2b(v.y);
    // involution: stored word (w ^ ((code&7)<<2)) holds original word w
    const int widx = code * 64 + (lane ^ ((code & 7) << 2));
    g_eh[widx] = (unsigned)h0 | ((unsigned)h1 << 16);

    float s = v.x * v.x + v.y * v.y;
    #pragma unroll
    for (int o = 32; o > 0; o >>= 1) s += __shfl_down(s, o);
    if (lane == 0) g_h[code] = 0.5f * s;
}

// ---------------- main: 1-pass bf16 MFMA + margin argmin + exact fp32 refine ----------------
__global__ __launch_bounds__(1024) void vq_main(
    const float* __restrict__ z, const float* __restrict__ emb, float* __restrict__ out)
{
    __shared__ char     smem[2 * 32768];      // double-buffered eh chunk (32KB each)
    __shared__ unsigned rv[BT * 4];           // per-token per-cq slot-best keys
    __shared__ unsigned bk_sh[BT];            // per-token global best key
    __shared__ int      lcnt[BT];
    __shared__ int      list[BT * CAP];
    __shared__ int      idx_sh[BT];
    __shared__ double   wred[16];
    __shared__ int      done_sh;

    const int tid  = threadIdx.x;
    const int lane = tid & 63;
    const int wid  = tid >> 6;                // 16 waves
    const int tq   = wid >> 2;                // token group (32 tokens)
    const int cq   = wid & 3;                 // code quarter (32 codes/chunk)
    const int l15  = lane & 15;
    const int lg   = lane >> 4;
    const long t0  = (long)blockIdx.x * BT;

    // ---- A fragments: 32 z-rows, bf16-hi only ----
    bf16x8 ah[2][4];
    #pragma unroll
    for (int m = 0; m < 2; ++m) {
        const long trow = t0 + tq * 32 + m * 16 + l15;
        #pragma unroll
        for (int kk = 0; kk < 4; ++kk) {
            const float4* zp = (const float4*)(z + trow * DIM + kk * 32 + lg * 8);
            float4 v0 = zp[0], v1 = zp[1];
            float xs[8] = {v0.x, v0.y, v0.z, v0.w, v1.x, v1.y, v1.z, v1.w};
            #pragma unroll
            for (int j = 0; j < 8; ++j) ah[m][kk][j] = (short)f2b(xs[j]);
        }
    }

    // swizzled LDS read offsets: row=l15, byte = row*256 + ((kk*64+lg*16) ^ ((row&7)<<4))
    const int xr = (l15 & 7) << 4;
    int loff[4];
    #pragma unroll
    for (int kk = 0; kk < 4; ++kk) loff[kk] = l15 * 256 + ((kk * 64 + lg * 16) ^ xr);

    unsigned b0[2][4], b1[2][4];              // 2-deep packed candidate keys per slot
    #pragma unroll
    for (int m = 0; m < 2; ++m)
        #pragma unroll
        for (int r = 0; r < 4; ++r) { b0[m][r] = 0xFFFFFFFFu; b1[m][r] = 0xFFFFFFFFu; }

    // prologue: stage chunk 0 (1024 thr x 16B = 16KB per round)
    {
        const int o = tid * 16;
        gll16((const char*)g_eh + o, smem + o);
        gll16((const char*)g_eh + 16384 + o, smem + 16384 + o);
    }
    __syncthreads();

    for (int ch = 0; ch < NCHUNK; ++ch) {
        const int cur = ch & 1;
        if (ch + 1 < NCHUNK) {
            const int  o  = tid * 16;
            const long go = (long)(ch + 1) * 32768;
            char* ldst = smem + (cur ^ 1) * 32768;
            gll16((const char*)g_eh + go + o, ldst + o);
            gll16((const char*)g_eh + go + 16384 + o, ldst + 16384 + o);
        }

        const char* base = smem + cur * 32768 + cq * 8192;
        const int   c0   = ch * NC + cq * 32 + l15;
        const float hv0  = g_h[c0];
        const float hv1  = g_h[c0 + 16];

        #pragma unroll
        for (int n = 0; n < 2; ++n) {
            bf16x8 bh[4];
            #pragma unroll
            for (int kk = 0; kk < 4; ++kk)
                bh[kk] = *(const bf16x8*)(base + n * 4096 + loff[kk]);
            f32x4 acc[2];
            #pragma unroll
            for (int m = 0; m < 2; ++m) acc[m] = (f32x4){0.f, 0.f, 0.f, 0.f};
            #pragma unroll
            for (int kk = 0; kk < 4; ++kk)
                #pragma unroll
                for (int m = 0; m < 2; ++m)
                    acc[m] = __builtin_amdgcn_mfma_f32_16x16x32_bf16(ah[m][kk], bh[kk], acc[m], 0, 0, 0);

            const float hvn = n ? hv1 : hv0;
            const int   c   = c0 + n * 16;
            #pragma unroll
            for (int m = 0; m < 2; ++m)
                #pragma unroll
                for (int r = 0; r < 4; ++r) {
                    unsigned k  = pkey(hvn - acc[m][r], c);
                    unsigned mx = max(b0[m][r], k);
                    b0[m][r] = min(b0[m][r], k);
                    b1[m][r] = min(b1[m][r], mx);
                }
        }
        __syncthreads();
    }

    // ---- global best key per token ----
    #pragma unroll
    for (int m = 0; m < 2; ++m)
        #pragma unroll
        for (int r = 0; r < 4; ++r) {
            unsigned k = b0[m][r];
            #pragma unroll
            for (int o = 1; o < 16; o <<= 1) k = min(k, (unsigned)__shfl_xor((int)k, o));
            if (l15 == 0) rv[(tq * 32 + m * 16 + lg * 4 + r) * 4 + cq] = k;
        }
    __syncthreads();
    if (tid < BT) {
        unsigned k = min(min(rv[tid * 4], rv[tid * 4 + 1]), min(rv[tid * 4 + 2], rv[tid * 4 + 3]));
        bk_sh[tid] = k;
        lcnt[tid]  = 0;
    }
    __syncthreads();

    // ---- collect candidates within margin of best ----
    #pragma unroll
    for (int m = 0; m < 2; ++m)
        #pragma unroll
        for (int r = 0; r < 4; ++r) {
            const int   t  = tq * 32 + m * 16 + lg * 4 + r;
            const float th = key2sc(bk_sh[t]) + MARGIN;
            if (key2sc(b0[m][r]) <= th) {
                int p = atomicAdd(&lcnt[t], 1);
                if (p < CAP) list[t * CAP + p] = (int)(b0[m][r] & 8191u);
            }
            if (key2sc(b1[m][r]) <= th) {
                int p = atomicAdd(&lcnt[t], 1);
                if (p < CAP) list[t * CAP + p] = (int)(b1[m][r] & 8191u);
            }
        }
    __syncthreads();

    // ---- exact fp32 refine: 8 tokens/wave, 8 lanes/token ----
    {
        const int t  = wid * 8 + (lane >> 3);
        const int li = lane & 7;
        const int cnt = min(lcnt[t], CAP);
        const float4* zt = (const float4*)(z + (t0 + t) * DIM) + li * 4;
        float4 zr0 = zt[0], zr1 = zt[1], zr2 = zt[2], zr3 = zt[3];
        float bsc = FLT_MAX; int bidx = KCB;
        for (int j = 0; j < cnt; ++j) {
            const int c = list[t * CAP + j];
            const float4* ec = (const float4*)(emb + (size_t)c * DIM) + li * 4;
            float4 e0 = ec[0], e1 = ec[1], e2 = ec[2], e3 = ec[3];
            float s = zr0.x*e0.x + zr0.y*e0.y + zr0.z*e0.z + zr0.w*e0.w
                    + zr1.x*e1.x + zr1.y*e1.y + zr1.z*e1.z + zr1.w*e1.w
                    + zr2.x*e2.x + zr2.y*e2.y + zr2.z*e2.z + zr2.w*e2.w
                    + zr3.x*e3.x + zr3.y*e3.y + zr3.z*e3.z + zr3.w*e3.w;
            #pragma unroll
            for (int o = 1; o < 8; o <<= 1) s += __shfl_xor(s, o);
            float sc = g_h[c] - s;
            if (sc < bsc || (sc == bsc && c < bidx)) { bsc = sc; bidx = c; }
        }
        if (li == 0) {
            idx_sh[t] = bidx;
            atomicAdd(&g_counts[bidx], 1u);
        }
    }
    __syncthreads();

    // ---- epilogue: gather e[idx], out = z + (zq - z), loss partial ----
    float lsum = 0.f;
    {
        const float4* zf4 = (const float4*)(z + t0 * DIM);
        const float4* ef4 = (const float4*)emb;
        float4*       of4 = (float4*)(out + t0 * DIM);
        #pragma unroll
        for (int r = 0; r < 4; ++r) {
            int f = r * 1024 + tid;
            int t = f >> 5, dw = f & 31;
            int ci = idx_sh[t];
            float4 e4 = ef4[(size_t)ci * 32 + dw];
            float4 z4 = zf4[f];
            float dx = e4.x - z4.x, dy = e4.y - z4.y;
            float dz = e4.z - z4.z, dw2 = e4.w - z4.w;
            lsum += dx * dx + dy * dy + dz * dz + dw2 * dw2;
            float4 o;
            o.x = z4.x + dx; o.y = z4.y + dy; o.z = z4.z + dz; o.w = z4.w + dw2;
            of4[f] = o;
        }
    }
    #pragma unroll
    for (int o = 32; o > 0; o >>= 1) lsum += __shfl_down(lsum, o);
    if (lane == 0) wred[wid] = (double)lsum;
    __syncthreads();
    if (tid == 0) {
        double s = 0.0;
        #pragma unroll
        for (int w = 0; w < 16; ++w) s += wred[w];
        atomicAdd(&g_loss, s);
    }

    // ---- last block: perplexity + commit loss ----
    __threadfence();
    if (tid == 0) done_sh = (atomicAdd(&g_done, 1u) == gridDim.x - 1) ? 1 : 0;
    __syncthreads();
    if (done_sh) {
        const int ntok    = (int)gridDim.x * BT;
        const int n_elems = ntok * DIM;
        double s = 0.0;
        for (int i = tid; i < KCB; i += 1024) {
            unsigned cnt = atomicAdd(&g_counts[i], 0u);
            float em = (float)cnt / (float)ntok;
            s += (double)(em * logf(em + 1e-8f));
        }
        #pragma unroll
        for (int o = 32; o > 0; o >>= 1) s += __shfl_down(s, o);
        if (lane == 0) wred[wid] = s;
        __syncthreads();
        if (tid == 0) {
            double tot = 0.0;
            #pragma unroll
            for (int w = 0; w < 16; ++w) tot += wred[w];
            double L = atomicAdd(&g_loss, 0.0);
            out[(size_t)n_elems]     = (float)(1.25 * L / (double)n_elems);
            out[(size_t)n_elems + 1] = expf((float)(-tot));
        }
    }
}

extern "C" void kernel_launch(void* const* d_in, const int* in_sizes, int n_in,
                              void* d_out, int out_size, void* d_ws, size_t ws_size,
                              hipStream_t stream)
{
    const float* z   = (const float*)d_in[0];
    const float* emb = (const float*)d_in[1];
    float* out = (float*)d_out;

    const int n_elems = in_sizes[0];        // 4194304
    const int ntok    = n_elems / DIM;      // 32768

    vq_prep<<<dim3(KCB / 4),   256,  0, stream>>>(emb);
    vq_main<<<dim3(ntok / BT), 1024, 0, stream>>>(z, emb, out);
}